// Round 6
// baseline (1078.786 us; speedup 1.0000x reference)
//
#include <hip/hip_runtime.h>
#include <math.h>

// Problem constants (B=2,H=12,Q=2048,K=2048,D=128,NPOS=512)
#define DD    128
#define NPOS  512
#define KK    2048
#define RPB   16        // rows per block = MFMA M dimension
#define BLK   1024      // 16 waves: one wave per row in phase 2

typedef __attribute__((ext_vector_type(8))) short short8_t;  // 8 bf16 (4 VGPRs)
typedef __attribute__((ext_vector_type(4))) float f32x4;

union BfPack {
    unsigned u[4];
    short8_t v;
};

__device__ __forceinline__ float sigmoidf_fast(float x) {
    // fast sigmoid: v_exp_f32 + v_rcp_f32 (no IEEE-div sequence)
    return __builtin_amdgcn_rcpf(1.0f + __expf(-x));
}

// truncate two fp32 to bf16, packed into one dword (hi<<16 | lo)
__device__ __forceinline__ unsigned pack_bf16(float lo, float hi) {
    return (__float_as_uint(hi) & 0xffff0000u) | (__float_as_uint(lo) >> 16);
}

__global__ __launch_bounds__(BLK, 8)
void cope_kernel(const float* __restrict__ query,     // [R, D]
                 const float* __restrict__ attn,      // [R, K]
                 const float* __restrict__ pos_emb,   // [D, NPOS]
                 const int*   __restrict__ npos_max_p,
                 float* __restrict__ out)              // [R, K]
{
    const int t    = threadIdx.x;
    const int wv   = t >> 6;       // wave id 0..15
    const int lane = t & 63;

    __shared__ float s_tab[RPB][NPOS + 1];   // +1 sentinel col for ifl+1 read

    const size_t row_base = (size_t)blockIdx.x * RPB;

    // ---------------- Phase 1: table GEMM via bf16 MFMA ----------------
    // Output [16 rows x 512 cols]; wave wv owns cols [wv*32, wv*32+32).
    {
        const int m  = lane & 15;
        const int g  = lane >> 4;
        const int n0 = wv * 32 + m;            // nt=0 column, nt=1 is +16

        f32x4 acc0 = {0.f, 0.f, 0.f, 0.f};
        f32x4 acc1 = {0.f, 0.f, 0.f, 0.f};

        #pragma unroll
        for (int kk = 0; kk < 4; ++kk) {
            const int k0 = kk * 32 + g * 8;

            // A fragment: 8 contiguous k of query row m
            const float* qp = query + (row_base + m) * DD + k0;
            f32x4 a0 = *reinterpret_cast<const f32x4*>(qp);
            f32x4 a1 = *reinterpret_cast<const f32x4*>(qp + 4);
            BfPack af;
            af.u[0] = pack_bf16(a0.x, a0.y);
            af.u[1] = pack_bf16(a0.z, a0.w);
            af.u[2] = pack_bf16(a1.x, a1.y);
            af.u[3] = pack_bf16(a1.z, a1.w);

            // B fragments: pos_emb[k][n], k strided by NPOS
            const float* bp = pos_emb + (size_t)k0 * NPOS + n0;
            float b0[8], b1[8];
            #pragma unroll
            for (int j = 0; j < 8; ++j) {
                b0[j] = bp[(size_t)j * NPOS];
                b1[j] = bp[(size_t)j * NPOS + 16];
            }
            BfPack bf0, bf1;
            #pragma unroll
            for (int j = 0; j < 4; ++j) {
                bf0.u[j] = pack_bf16(b0[2 * j], b0[2 * j + 1]);
                bf1.u[j] = pack_bf16(b1[2 * j], b1[2 * j + 1]);
            }

            acc0 = __builtin_amdgcn_mfma_f32_16x16x32_bf16(af.v, bf0.v, acc0, 0, 0, 0);
            acc1 = __builtin_amdgcn_mfma_f32_16x16x32_bf16(af.v, bf1.v, acc1, 0, 0, 0);
        }

        #pragma unroll
        for (int r = 0; r < 4; ++r) {
            s_tab[g * 4 + r][n0]      = acc0[r];
            s_tab[g * 4 + r][n0 + 16] = acc1[r];
        }
        if (t < RPB) s_tab[t][NPOS] = 0.0f;   // sentinel (w=0 there)
    }
    __syncthreads();

    // ---------------- Phase 2: lane owns 32 CONTIGUOUS elements ----------
    // One 6-step wave scan per row (vs 8 before); in-lane suffix is pure VALU.
    const size_t row = row_base + wv;
    const float* arow = attn + row * (size_t)KK;
    float*       orow = out  + row * (size_t)KK;
    const float* tab  = s_tab[wv];

    const float clampv = (float)(*npos_max_p - 1);
    const int   e0     = lane * 32;    // this lane's first element

    union { f32x4 v4[8]; float f[32]; } d;

    // loads: instr c=0 covers the full 8KB row (64 lanes x 128B stride),
    // c=1..7 are L1 hits.
    #pragma unroll
    for (int c = 0; c < 8; ++c)
        d.v4[c] = *reinterpret_cast<const f32x4*>(arow + e0 + c * 4);

    // sigmoid (32 independent chains -> good ILP)
    #pragma unroll
    for (int j = 0; j < 32; ++j)
        d.f[j] = sigmoidf_fast(d.f[j]);

    // in-lane inclusive suffix sum
    #pragma unroll
    for (int j = 30; j >= 0; --j)
        d.f[j] += d.f[j + 1];

    // one wave-level suffix scan of lane totals
    const float tot = d.f[0];
    float incl = tot;
    #pragma unroll
    for (int off = 1; off < 64; off <<= 1) {
        float u = __shfl_down(incl, off);
        incl += (lane + off < 64) ? u : 0.0f;
    }
    const float base = incl - tot;    // sum of gates in lanes strictly after

    // pos -> gather -> lerp -> NT store
    #pragma unroll
    for (int c = 0; c < 8; ++c) {
        f32x4 res;
        #pragma unroll
        for (int j = 0; j < 4; ++j) {
            float pos = fminf(d.f[c * 4 + j] + base, clampv);
            int   ifl = (int)pos;          // pos >= 0, trunc == floor
            float wgt = pos - (float)ifl;
            float lf  = tab[ifl];
            float lc  = tab[ifl + 1];      // sentinel makes ifl=511 safe
            res[j] = fmaf(wgt, lc - lf, lf);
        }
        __builtin_nontemporal_store(res,
            reinterpret_cast<f32x4*>(orow + e0 + c * 4));
    }
}

extern "C" void kernel_launch(void* const* d_in, const int* in_sizes, int n_in,
                              void* d_out, int out_size, void* d_ws, size_t ws_size,
                              hipStream_t stream) {
    const float* query   = (const float*)d_in[0];
    const float* attn    = (const float*)d_in[1];
    const float* pos_emb = (const float*)d_in[2];
    const int*   nposp   = (const int*)d_in[3];
    float*       outp    = (float*)d_out;

    const int rows   = in_sizes[1] / KK;   // B*H*Q = 49152
    const int blocks = rows / RPB;         // 3072

    cope_kernel<<<blocks, BLK, 0, stream>>>(query, attn, pos_emb, nposp, outp);
}

// Round 7
// 285.747 us; speedup vs baseline: 3.7753x; 3.7753x over previous
//
#include <hip/hip_runtime.h>
#include <math.h>

// Problem constants (B=2,H=12,Q=2048,K=2048,D=128,NPOS=512)
#define DD    128
#define NPOS  512
#define KK    2048
#define RPB   16        // rows per block = MFMA M dimension
#define BLK   1024      // 16 waves: one wave per row in phase 2

typedef __attribute__((ext_vector_type(8))) short short8_t;  // 8 bf16 (4 VGPRs)
typedef __attribute__((ext_vector_type(4))) float f32x4;

union BfPack {
    unsigned u[4];
    short8_t v;
};

__device__ __forceinline__ float sigmoidf_fast(float x) {
    // v_exp_f32 + v_rcp_f32, no IEEE-div sequence
    return __builtin_amdgcn_rcpf(1.0f + __expf(-x));
}

// truncate two fp32 to bf16, packed into one dword (hi<<16 | lo)
__device__ __forceinline__ unsigned pack_bf16(float lo, float hi) {
    return (__float_as_uint(hi) & 0xffff0000u) | (__float_as_uint(lo) >> 16);
}

__global__ __launch_bounds__(BLK, 8)
void cope_kernel(const float* __restrict__ query,     // [R, D]
                 const float* __restrict__ attn,      // [R, K]
                 const float* __restrict__ pos_emb,   // [D, NPOS]
                 const int*   __restrict__ npos_max_p,
                 float* __restrict__ out)              // [R, K]
{
    const int t    = threadIdx.x;
    const int wv   = t >> 6;       // wave id 0..15
    const int lane = t & 63;

    __shared__ float s_tab[RPB][NPOS + 1];   // +1 sentinel col for ifl+1 read

    const size_t row_base = (size_t)blockIdx.x * RPB;

    // ---------------- Phase 1: table GEMM via bf16 MFMA ----------------
    // Output [16 rows x 512 cols]; wave wv owns cols [wv*32, wv*32+32).
    {
        const int m  = lane & 15;
        const int g  = lane >> 4;
        const int n0 = wv * 32 + m;            // nt=0 column, nt=1 is +16

        f32x4 acc0 = {0.f, 0.f, 0.f, 0.f};
        f32x4 acc1 = {0.f, 0.f, 0.f, 0.f};

        #pragma unroll
        for (int kk = 0; kk < 4; ++kk) {
            const int k0 = kk * 32 + g * 8;

            // A fragment: 8 contiguous k of query row m
            const float* qp = query + (row_base + m) * DD + k0;
            f32x4 a0 = *reinterpret_cast<const f32x4*>(qp);
            f32x4 a1 = *reinterpret_cast<const f32x4*>(qp + 4);
            BfPack af;
            af.u[0] = pack_bf16(a0.x, a0.y);
            af.u[1] = pack_bf16(a0.z, a0.w);
            af.u[2] = pack_bf16(a1.x, a1.y);
            af.u[3] = pack_bf16(a1.z, a1.w);

            // B fragments: pos_emb[k][n], k strided by NPOS
            const float* bp = pos_emb + (size_t)k0 * NPOS + n0;
            float b0[8], b1[8];
            #pragma unroll
            for (int j = 0; j < 8; ++j) {
                b0[j] = bp[(size_t)j * NPOS];
                b1[j] = bp[(size_t)j * NPOS + 16];
            }
            BfPack bf0, bf1;
            #pragma unroll
            for (int j = 0; j < 4; ++j) {
                bf0.u[j] = pack_bf16(b0[2 * j], b0[2 * j + 1]);
                bf1.u[j] = pack_bf16(b1[2 * j], b1[2 * j + 1]);
            }

            acc0 = __builtin_amdgcn_mfma_f32_16x16x32_bf16(af.v, bf0.v, acc0, 0, 0, 0);
            acc1 = __builtin_amdgcn_mfma_f32_16x16x32_bf16(af.v, bf1.v, acc1, 0, 0, 0);
        }

        #pragma unroll
        for (int r = 0; r < 4; ++r) {
            s_tab[g * 4 + r][n0]      = acc0[r];
            s_tab[g * 4 + r][n0 + 16] = acc1[r];
        }
        if (t < RPB) s_tab[t][NPOS] = 0.0f;   // sentinel (w=0 there)
    }
    __syncthreads();

    // ---------------- Phase 2: 4 chunks of 512; lane owns 8 contiguous ----
    // 4 wave-scans per row (was 8). In-lane suffix work identical.
    const size_t row = row_base + wv;
    const float* arow = attn + row * (size_t)KK;
    float*       orow = out  + row * (size_t)KK;
    const float* tab  = s_tab[wv];

    const float clampv = (float)(*npos_max_p - 1);

    f32x4 suff[4][2];   // in-lane inclusive suffix sums (becomes pos)
    float lct[4];       // lane-chunk totals
    float incl[4];      // wave-suffix-inclusive scan of lane totals

    #pragma unroll
    for (int c = 0; c < 4; ++c) {
        const float* p = arow + c * 512 + lane * 8;
        f32x4 g0 = *reinterpret_cast<const f32x4*>(p);
        f32x4 g1 = *reinterpret_cast<const f32x4*>(p + 4);

        // sigmoid (8 independent chains)
        f32x4 s0, s1;
        #pragma unroll
        for (int j = 0; j < 4; ++j) {
            s0[j] = sigmoidf_fast(g0[j]);
            s1[j] = sigmoidf_fast(g1[j]);
        }

        // in-lane inclusive suffix over the 8 elements
        suff[c][1][3] = s1[3];
        suff[c][1][2] = s1[2] + suff[c][1][3];
        suff[c][1][1] = s1[1] + suff[c][1][2];
        suff[c][1][0] = s1[0] + suff[c][1][1];
        suff[c][0][3] = s0[3] + suff[c][1][0];
        suff[c][0][2] = s0[2] + suff[c][0][3];
        suff[c][0][1] = s0[1] + suff[c][0][2];
        suff[c][0][0] = s0[0] + suff[c][0][1];
        lct[c] = suff[c][0][0];

        // wave-level inclusive suffix scan (64 lanes)
        float v = lct[c];
        #pragma unroll
        for (int off = 1; off < 64; off <<= 1) {
            float u = __shfl_down(v, off);
            if (lane + off < 64) v += u;
        }
        incl[c] = v;
    }

    // cross-chunk suffix offsets (same value on all lanes)
    float Tc[4];
    #pragma unroll
    for (int c = 0; c < 4; ++c) Tc[c] = __shfl(incl[c], 0);
    float offc = 0.0f;
    #pragma unroll
    for (int c = 3; c >= 0; --c) {
        float base = offc + (incl[c] - lct[c]);
        #pragma unroll
        for (int h = 0; h < 2; ++h)
            #pragma unroll
            for (int j = 0; j < 4; ++j)
                suff[c][h][j] = fminf(suff[c][h][j] + base, clampv);  // = pos
        offc += Tc[c];
    }

    // gather + lerp + NT store
    #pragma unroll
    for (int c = 0; c < 4; ++c) {
        float* po = orow + c * 512 + lane * 8;
        #pragma unroll
        for (int h = 0; h < 2; ++h) {
            f32x4 res;
            #pragma unroll
            for (int j = 0; j < 4; ++j) {
                float pos = suff[c][h][j];
                int   ifl = (int)pos;          // pos >= 0, trunc == floor
                float wgt = pos - (float)ifl;
                float lf  = tab[ifl];
                float lc  = tab[ifl + 1];      // sentinel makes ifl=511 safe
                res[j] = fmaf(wgt, lc - lf, lf);
            }
            __builtin_nontemporal_store(res,
                reinterpret_cast<f32x4*>(po + h * 4));
        }
    }
}

extern "C" void kernel_launch(void* const* d_in, const int* in_sizes, int n_in,
                              void* d_out, int out_size, void* d_ws, size_t ws_size,
                              hipStream_t stream) {
    const float* query   = (const float*)d_in[0];
    const float* attn    = (const float*)d_in[1];
    const float* pos_emb = (const float*)d_in[2];
    const int*   nposp   = (const int*)d_in[3];
    float*       outp    = (float*)d_out;

    const int rows   = in_sizes[1] / KK;   // B*H*Q = 49152
    const int blocks = rows / RPB;         // 3072

    cope_kernel<<<blocks, BLK, 0, stream>>>(query, attn, pos_emb, nposp, outp);
}

// Round 8
// 170.950 us; speedup vs baseline: 6.3105x; 1.6715x over previous
//
#include <hip/hip_runtime.h>
#include <math.h>

// Problem constants (B=2,H=12,Q=2048,K=2048,D=128,NPOS=512)
#define DD    128
#define NPOS  512
#define KK    2048
#define RPB   16        // rows per block = MFMA M dimension
#define BLK   1024      // 16 waves: one wave per row in phase 2

typedef __attribute__((ext_vector_type(8))) short short8_t;  // 8 bf16 (4 VGPRs)
typedef __attribute__((ext_vector_type(4))) float f32x4;

union BfPack {
    unsigned u[4];
    short8_t v;
};

__device__ __forceinline__ float sigmoidf_fast(float x) {
    // v_exp_f32 + v_rcp_f32, no IEEE-div sequence
    return __builtin_amdgcn_rcpf(1.0f + __expf(-x));
}

// truncate two fp32 to bf16, packed into one dword (hi<<16 | lo)
__device__ __forceinline__ unsigned pack_bf16(float lo, float hi) {
    return (__float_as_uint(hi) & 0xffff0000u) | (__float_as_uint(lo) >> 16);
}

__global__ __launch_bounds__(BLK, 8)
void cope_kernel(const float* __restrict__ query,     // [R, D]
                 const float* __restrict__ attn,      // [R, K]
                 const float* __restrict__ pos_emb,   // [D, NPOS]
                 const int*   __restrict__ npos_max_p,
                 float* __restrict__ out)              // [R, K]
{
    const int t    = threadIdx.x;
    const int wv   = t >> 6;       // wave id 0..15
    const int lane = t & 63;

    __shared__ float s_tab[RPB][NPOS + 1];   // +1 sentinel col for ifl+1 read

    const size_t row_base = (size_t)blockIdx.x * RPB;

    // ---------------- Phase 1: table GEMM via bf16 MFMA ----------------
    // Output [16 rows x 512 cols]; wave wv owns cols [wv*32, wv*32+32).
    {
        const int m  = lane & 15;
        const int g  = lane >> 4;
        const int n0 = wv * 32 + m;            // nt=0 column, nt=1 is +16

        f32x4 acc0 = {0.f, 0.f, 0.f, 0.f};
        f32x4 acc1 = {0.f, 0.f, 0.f, 0.f};

        #pragma unroll
        for (int kk = 0; kk < 4; ++kk) {
            const int k0 = kk * 32 + g * 8;

            // A fragment: 8 contiguous k of query row m
            const float* qp = query + (row_base + m) * DD + k0;
            f32x4 a0 = *reinterpret_cast<const f32x4*>(qp);
            f32x4 a1 = *reinterpret_cast<const f32x4*>(qp + 4);
            BfPack af;
            af.u[0] = pack_bf16(a0.x, a0.y);
            af.u[1] = pack_bf16(a0.z, a0.w);
            af.u[2] = pack_bf16(a1.x, a1.y);
            af.u[3] = pack_bf16(a1.z, a1.w);

            // B fragments: pos_emb[k][n], k strided by NPOS
            const float* bp = pos_emb + (size_t)k0 * NPOS + n0;
            float b0[8], b1[8];
            #pragma unroll
            for (int j = 0; j < 8; ++j) {
                b0[j] = bp[(size_t)j * NPOS];
                b1[j] = bp[(size_t)j * NPOS + 16];
            }
            BfPack bf0, bf1;
            #pragma unroll
            for (int j = 0; j < 4; ++j) {
                bf0.u[j] = pack_bf16(b0[2 * j], b0[2 * j + 1]);
                bf1.u[j] = pack_bf16(b1[2 * j], b1[2 * j + 1]);
            }

            acc0 = __builtin_amdgcn_mfma_f32_16x16x32_bf16(af.v, bf0.v, acc0, 0, 0, 0);
            acc1 = __builtin_amdgcn_mfma_f32_16x16x32_bf16(af.v, bf1.v, acc1, 0, 0, 0);
        }

        #pragma unroll
        for (int r = 0; r < 4; ++r) {
            s_tab[g * 4 + r][n0]      = acc0[r];
            s_tab[g * 4 + r][n0 + 16] = acc1[r];
        }
        if (t < RPB) s_tab[t][NPOS] = 0.0f;   // sentinel (w=0 there)
    }
    __syncthreads();

    // ---------------- Phase 2: per-wave suffix scan + gather ----------------
    const size_t row = row_base + wv;
    const float* arow = attn + row * (size_t)KK;
    float*       orow = out  + row * (size_t)KK;
    const float* tab  = s_tab[wv];

    const float clampv = (float)(*npos_max_p - 1);

    // 2048 elems per row: 8 chunks of 256; lane owns 4 contiguous elems/chunk.
    float suff[8][4];   // within-lane suffix sums (inclusive)
    float lct[8];       // lane-chunk totals
    float incl[8];      // wave-suffix-inclusive scan of lane totals

    #pragma unroll
    for (int c = 0; c < 8; ++c) {
        f32x4 gv = *reinterpret_cast<const f32x4*>(arow + c * 256 + lane * 4);
        float s0 = sigmoidf_fast(gv.x);
        float s1 = sigmoidf_fast(gv.y);
        float s2 = sigmoidf_fast(gv.z);
        float s3 = sigmoidf_fast(gv.w);
        suff[c][3] = s3;
        suff[c][2] = s2 + suff[c][3];
        suff[c][1] = s1 + suff[c][2];
        suff[c][0] = s0 + suff[c][1];
        lct[c] = suff[c][0];

        // wave-level inclusive suffix scan (64 lanes)
        float v = lct[c];
        #pragma unroll
        for (int off = 1; off < 64; off <<= 1) {
            float u = __shfl_down(v, off);
            if (lane + off < 64) v += u;
        }
        incl[c] = v;
    }

    // cross-chunk suffix offsets (same value on all lanes)
    float Tc[8];
    #pragma unroll
    for (int c = 0; c < 8; ++c) Tc[c] = __shfl(incl[c], 0);
    float offc[8];
    offc[7] = 0.0f;
    #pragma unroll
    for (int c = 6; c >= 0; --c) offc[c] = offc[c + 1] + Tc[c + 1];

    // interpolate + store (non-temporal: output is never re-read)
    #pragma unroll
    for (int c = 0; c < 8; ++c) {
        float base = offc[c] + (incl[c] - lct[c]);
        f32x4 res;
        #pragma unroll
        for (int j = 0; j < 4; ++j) {
            float pos = fminf(suff[c][j] + base, clampv);
            int   ifl = (int)pos;          // pos >= 0, trunc == floor
            float wgt = pos - (float)ifl;
            float lf  = tab[ifl];
            float lc  = tab[ifl + 1];      // sentinel makes ifl=511 safe
            res[j] = fmaf(wgt, lc - lf, lf);
        }
        __builtin_nontemporal_store(res, reinterpret_cast<f32x4*>(orow + c * 256 + lane * 4));
    }
}

extern "C" void kernel_launch(void* const* d_in, const int* in_sizes, int n_in,
                              void* d_out, int out_size, void* d_ws, size_t ws_size,
                              hipStream_t stream) {
    const float* query   = (const float*)d_in[0];
    const float* attn    = (const float*)d_in[1];
    const float* pos_emb = (const float*)d_in[2];
    const int*   nposp   = (const int*)d_in[3];
    float*       outp    = (float*)d_out;

    const int rows   = in_sizes[1] / KK;   // B*H*Q = 49152
    const int blocks = rows / RPB;         // 3072

    cope_kernel<<<blocks, BLK, 0, stream>>>(query, attn, pos_emb, nposp, outp);
}